// Round 1
// baseline (375.779 us; speedup 1.0000x reference)
//
#include <hip/hip_runtime.h>
#include <math.h>

#define BB 64
#define CC 256
#define HWSZ 1024          // 32*32
#define CENTER_IDX 528     // 16*32 + 16

// ---- workspace layout (float offsets) ----
// wT  [257][256]  transposed conv_w                : [0, 65792)
// dot [2*64][1024]                                 : [65792, 196864)
// accA[2*64][256] sum of attn                      : [196864, 229632)
// accX[2*64][256] sum of x*attn                    : [229632, 262400)
#define WT_OFF   0
#define DOT_OFF  65792
#define ACCA_OFF 196864
#define ACCX_OFF 229632

// init: transpose conv_w into ws, zero accumulators (ws is re-poisoned 0xAA each call)
__global__ void k_init(const float* __restrict__ conv_w, float* __restrict__ ws) {
    int idx = blockIdx.x * 256 + threadIdx.x;
    if (idx < 257 * 256) {
        int o = idx / 257;
        int c = idx - o * 257;          // idx consecutive -> c consecutive: coalesced read
        ws[WT_OFF + c * 256 + o] = conv_w[idx];
    }
    if (idx < 65536) {
        ws[ACCA_OFF + idx] = 0.0f;      // zeroes accA then accX (contiguous 65536 floats)
    }
}

// dot[b,hw] = (1/256) * sum_c x[b,c,hw] * x[b,c,center]
__global__ __launch_bounds__(256) void k_dot(const float* __restrict__ x1,
                                             const float* __restrict__ x2,
                                             float* __restrict__ ws) {
    int blk = blockIdx.x;          // 0..511
    int xb  = blk >> 2;            // 0..127  (x*64 + b)
    int q   = blk & 3;             // quarter of hw
    const float* x = (xb < 64) ? x1 : x2;
    int b = xb & 63;
    const float* xp = x + (size_t)b * (CC * HWSZ);

    __shared__ float s_center[CC];
    int tid = threadIdx.x;
    s_center[tid] = xp[tid * HWSZ + CENTER_IDX];
    __syncthreads();

    int hw = q * 256 + tid;
    float acc = 0.f;
    #pragma unroll 4
    for (int c = 0; c < CC; ++c) {
        acc += xp[c * HWSZ + hw] * s_center[c];
    }
    ws[DOT_OFF + xb * HWSZ + hw] = acc * (1.0f / 256.0f);
}

// main fused GEMM: z = wT^T(256x256) @ x[b] (256x1024) tile 128x128, + dot channel,
// sigmoid, fused row reductions (sum attn, sum x*attn) -> global atomics
__global__ __launch_bounds__(256, 2)
void k_main(const float* __restrict__ x1, const float* __restrict__ x2,
            float* __restrict__ ws) {
    int hw0 = blockIdx.x * 128;          // 8 tiles
    int o0  = blockIdx.y * 128;          // 2 tiles
    int xb  = blockIdx.z;                // 0..127
    const float* x = (xb < 64) ? x1 : x2;
    int b = xb & 63;
    const float* xp  = x + (size_t)b * (CC * HWSZ);
    const float* wT  = ws + WT_OFF;
    const float* dpt = ws + DOT_OFF + xb * HWSZ;
    float* accA = ws + ACCA_OFF + xb * CC;
    float* accX = ws + ACCX_OFF + xb * CC;

    __shared__ float sX[16][128];
    __shared__ float sW[16][128];

    int tid = threadIdx.x;
    int tx = tid & 15;        // hw direction (8 cols each)
    int ty = tid >> 4;        // o  direction (8 rows each)

    float acc[8][8];
    #pragma unroll
    for (int i = 0; i < 8; ++i)
        #pragma unroll
        for (int j = 0; j < 8; ++j) acc[i][j] = 0.f;

    int sxf = tid & 31;       // float4 index within a 128-float row
    int sxr = tid >> 5;       // row 0..7 (also handles row+8)

    for (int c0 = 0; c0 < 256; c0 += 16) {
        float4 vx0 = *((const float4*)(xp + (size_t)(c0 + sxr)     * HWSZ + hw0) + sxf);
        float4 vx1 = *((const float4*)(xp + (size_t)(c0 + sxr + 8) * HWSZ + hw0) + sxf);
        float4 vw0 = *((const float4*)(wT + (c0 + sxr)     * 256 + o0) + sxf);
        float4 vw1 = *((const float4*)(wT + (c0 + sxr + 8) * 256 + o0) + sxf);
        __syncthreads();   // previous iteration's readers done before overwrite
        ((float4*)sX[sxr    ])[sxf] = vx0;
        ((float4*)sX[sxr + 8])[sxf] = vx1;
        ((float4*)sW[sxr    ])[sxf] = vw0;
        ((float4*)sW[sxr + 8])[sxf] = vw1;
        __syncthreads();
        #pragma unroll
        for (int k = 0; k < 16; ++k) {
            float4 a0 = ((const float4*)sW[k])[ty * 2];
            float4 a1 = ((const float4*)sW[k])[ty * 2 + 1];
            float4 b0 = ((const float4*)sX[k])[tx * 2];
            float4 b1 = ((const float4*)sX[k])[tx * 2 + 1];
            float av[8] = {a0.x, a0.y, a0.z, a0.w, a1.x, a1.y, a1.z, a1.w};
            float bv[8] = {b0.x, b0.y, b0.z, b0.w, b1.x, b1.y, b1.z, b1.w};
            #pragma unroll
            for (int i = 0; i < 8; ++i)
                #pragma unroll
                for (int j = 0; j < 8; ++j)
                    acc[i][j] += av[i] * bv[j];
        }
    }

    // k = 256: the concatenated "dot" channel
    {
        float wv[8], dv[8];
        #pragma unroll
        for (int i = 0; i < 8; ++i) wv[i] = wT[256 * 256 + o0 + ty * 8 + i];
        #pragma unroll
        for (int j = 0; j < 8; ++j) dv[j] = dpt[hw0 + tx * 8 + j];
        #pragma unroll
        for (int i = 0; i < 8; ++i)
            #pragma unroll
            for (int j = 0; j < 8; ++j) acc[i][j] += wv[i] * dv[j];
    }

    // epilogue: attn = sigmoid(z); per-o partial sums over this hw tile
    #pragma unroll
    for (int i = 0; i < 8; ++i) {
        int o = o0 + ty * 8 + i;
        const float4* xr = (const float4*)(xp + (size_t)o * HWSZ + hw0) + tx * 2;
        float4 xv0 = xr[0], xv1 = xr[1];
        float xs[8] = {xv0.x, xv0.y, xv0.z, xv0.w, xv1.x, xv1.y, xv1.z, xv1.w};
        float sA = 0.f, sXv = 0.f;
        #pragma unroll
        for (int j = 0; j < 8; ++j) {
            float a = 1.0f / (1.0f + __expf(-acc[i][j]));
            sA  += a;
            sXv += xs[j] * a;
        }
        // reduce across the 16 tx lanes (lane = (ty%4)*16 + tx within the wave)
        #pragma unroll
        for (int m = 1; m < 16; m <<= 1) {
            sA  += __shfl_xor(sA,  m, 64);
            sXv += __shfl_xor(sXv, m, 64);
        }
        if (tx == 0) {
            atomicAdd(&accA[o], sA);
            atomicAdd(&accX[o], sXv);
        }
    }
}

// out[b,o] = accX0/(accA0+eps) + accX1/(accA1+eps)
__global__ void k_out(const float* __restrict__ ws, float* __restrict__ out) {
    int idx = blockIdx.x * 256 + threadIdx.x;   // b*256 + o
    if (idx < BB * CC) {
        int b = idx >> 8, o = idx & 255;
        float a0 = ws[ACCA_OFF + b * 256 + o];
        float p0 = ws[ACCX_OFF + b * 256 + o];
        float a1 = ws[ACCA_OFF + (64 + b) * 256 + o];
        float p1 = ws[ACCX_OFF + (64 + b) * 256 + o];
        out[idx] = p0 / (a0 + 1e-8f) + p1 / (a1 + 1e-8f);
    }
}

extern "C" void kernel_launch(void* const* d_in, const int* in_sizes, int n_in,
                              void* d_out, int out_size, void* d_ws, size_t ws_size,
                              hipStream_t stream) {
    const float* x1     = (const float*)d_in[0];
    const float* x2     = (const float*)d_in[1];
    const float* conv_w = (const float*)d_in[2];
    // d_in[3..6] (caLayer params) are dead: softmax over a size-1 axis == 1.
    float* ws  = (float*)d_ws;
    float* out = (float*)d_out;

    k_init<<<257, 256, 0, stream>>>(conv_w, ws);
    k_dot<<<512, 256, 0, stream>>>(x1, x2, ws);
    dim3 g(8, 2, 128);
    k_main<<<g, 256, 0, stream>>>(x1, x2, ws);
    k_out<<<64, 256, 0, stream>>>(ws, out);
}

// Round 3
// 249.297 us; speedup vs baseline: 1.5074x; 1.5074x over previous
//
#include <hip/hip_runtime.h>
#include <hip/hip_bf16.h>
#include <math.h>

// dtypes for MFMA
typedef __bf16 bf16x8 __attribute__((ext_vector_type(8)));
typedef float  f32x16 __attribute__((ext_vector_type(16)));

// ---- workspace layout (float offsets) ----
// wfrag : 65536 bf16 (fragment-ready W)          [0, 32768) floats
// wlast : 256 fp32 (column 256 of conv_w)        [32768, 33024)
// dot   : [128][1024] fp32                       [33024, 164096)
// accA  : [128][256] fp32                        [164096, 196864)
// accX  : [128][256] fp32                        [196864, 229632)
#define WLAST_OFF 32768
#define DOT_OFF   33024
#define ACCA_OFF  164096
#define ACCX_OFF  196864

static __device__ __forceinline__ unsigned f2bf_u(float f) {
    unsigned u = __builtin_bit_cast(unsigned, f);
    return (u + 0x7fffu + ((u >> 16) & 1u)) >> 16;                     // RNE
}

static __device__ __forceinline__ unsigned pkbf(float a, float b) {
    return (f2bf_u(b) << 16) | f2bf_u(a);                              // a in low 16
}

// k_init: build fragment-ready bf16 W + wlast + zero accumulators.
// A-frag layout (32x32x16): lane l holds A[o = ot*32 + (l&31)][k = S*16 + (l>>5)*8 + j], j=0..7.
// flat bf16 idx = ((S*8 + ot)*64 + l)*8 + j  -> one coalesced dwordx4/lane at use time.
__global__ void k_init(const float* __restrict__ conv_w, float* __restrict__ ws) {
    int idx = blockIdx.x * 256 + threadIdx.x;       // 0..65535
    int j  = idx & 7;
    int l  = (idx >> 3) & 63;
    int ot = (idx >> 9) & 7;
    int S  = idx >> 12;                             // 0..15
    int o  = ot * 32 + (l & 31);
    int k  = S * 16 + (l >> 5) * 8 + j;
    ((unsigned short*)ws)[idx] = (unsigned short)f2bf_u(conv_w[o * 257 + k]);
    if (idx < 256) ws[WLAST_OFF + idx] = conv_w[idx * 257 + 256];
    ws[ACCA_OFF + idx] = 0.0f;                      // zeroes accA then accX (65536 floats)
}

// k_prep: dot[b,hw] = (1/256) * sum_c x[b,c,hw]*x[b,c,center]
// c split over 4 thread-groups (64-deep independent FMA chains), LDS combine.
__global__ __launch_bounds__(256) void k_prep(const float* __restrict__ x1,
                                              const float* __restrict__ x2,
                                              float* __restrict__ ws) {
    int blk = blockIdx.x;              // 0..511
    int xb  = blk >> 2;
    int hq  = blk & 3;
    const float* xp = ((xb < 64) ? x1 : x2) + (size_t)(xb & 63) * (256 * 1024);

    __shared__ float scen[256];
    __shared__ float spart[4][256];
    int tid = threadIdx.x;
    scen[tid] = xp[tid * 1024 + 528];             // center = (16,16)
    __syncthreads();

    int g = tid >> 6, ln = tid & 63;
    const float* base = xp + (size_t)g * 64 * 1024 + hq * 256 + ln * 4;
    float4 acc = make_float4(0.f, 0.f, 0.f, 0.f);
    #pragma unroll 8
    for (int cc = 0; cc < 64; ++cc) {
        float4 v = *(const float4*)(base + (size_t)cc * 1024);
        float c = scen[g * 64 + cc];
        acc.x += v.x * c; acc.y += v.y * c; acc.z += v.z * c; acc.w += v.w * c;
    }
    *(float4*)&spart[g][ln * 4] = acc;
    __syncthreads();
    float s = spart[0][tid] + spart[1][tid] + spart[2][tid] + spart[3][tid];
    ws[DOT_OFF + xb * 1024 + hq * 256 + tid] = s * (1.0f / 256.0f);
}

// k_main: bf16 MFMA GEMM z[o,hw] = W@X, + fp32 rank-1 dot term, sigmoid,
// fused reductions (sum attn, sum x*attn) via butterfly + atomics.
__global__ __launch_bounds__(256)
void k_main(const float* __restrict__ x1, const float* __restrict__ x2,
            float* __restrict__ ws) {
    int bx = blockIdx.x;               // hw tile (128)
    int by = blockIdx.y;               // o half (128)
    int xb = blockIdx.z;               // 0..127
    const float* xp = ((xb < 64) ? x1 : x2) + (size_t)(xb & 63) * (256 * 1024);
    const unsigned short* wfrag = (const unsigned short*)ws;
    const float* wlast = ws + WLAST_OFF;
    const float* dptr  = ws + DOT_OFF + xb * 1024;
    float* accA = ws + ACCA_OFF + xb * 256;
    float* accX = ws + ACCX_OFF + xb * 256;
    int hw0 = bx * 128;

    int tid = threadIdx.x;
    int l = tid & 63, w = tid >> 6;
    int lw = l & 31, q = l >> 5;
    int wo = (w & 1) * 64, wh = (w >> 1) * 64;

    // LDS: 2 buffers x 128 hw-rows x 16 words (32 bf16 of k), XOR-swizzled.
    __shared__ unsigned sx[2][2048];

    f32x16 acc[2][2];
    #pragma unroll
    for (int i = 0; i < 2; ++i)
        #pragma unroll
        for (int j = 0; j < 2; ++j)
            #pragma unroll
            for (int e = 0; e < 16; ++e) acc[i][j][e] = 0.0f;

    int hwi = tid & 31, kq = tid >> 5;
    const float* xst = xp + (size_t)(kq * 4) * 1024 + hw0 + hwi * 4;

    // transposing staging write: thread (hwi,kq) covers rows hwi*4+{0..3} x kwords {2kq,2kq+1}
    auto stage_write = [&](unsigned* buf, float4 a0, float4 a1, float4 a2, float4 a3) {
        float m0[4] = {a0.x, a0.y, a0.z, a0.w};
        float m1[4] = {a1.x, a1.y, a1.z, a1.w};
        float m2[4] = {a2.x, a2.y, a2.z, a2.w};
        float m3[4] = {a3.x, a3.y, a3.z, a3.w};
        #pragma unroll
        for (int ii = 0; ii < 4; ++ii) {
            int i = (hwi + ii) & 3;                       // rotate rows across lanes
            int hwr = hwi * 4 + i;
            unsigned lo = pkbf(m0[i], m1[i]);             // k even low
            unsigned hi = pkbf(m2[i], m3[i]);
            int idx = hwr * 16 + ((kq * 2) ^ (((hwr >> 1) & 7) << 1));
            *(uint2*)&buf[idx] = make_uint2(lo, hi);
        }
    };

    auto loadA = [&](int S, int it) -> bf16x8 {
        return *(const bf16x8*)(wfrag + ((size_t)((S * 8 + (by * 4 + (w & 1) * 2 + it)) * 64 + l) * 8));
    };
    auto loadB = [&](const unsigned* buf, int sub, int jt) -> bf16x8 {
        int hwr = wh + jt * 32 + lw;
        int sg = ((hwr >> 1) & 7) << 1;
        int base = hwr * 16;
        int kb = sub * 8 + q * 4;
        uint2 p0 = *(const uint2*)&buf[base + (kb ^ sg)];
        uint2 p1 = *(const uint2*)&buf[base + ((kb + 2) ^ sg)];
        uint4 u = make_uint4(p0.x, p0.y, p1.x, p1.y);
        return __builtin_bit_cast(bf16x8, u);
    };

    // prologue: stage 0
    float4 r0 = *(const float4*)(xst);
    float4 r1 = *(const float4*)(xst + 1024);
    float4 r2 = *(const float4*)(xst + 2048);
    float4 r3 = *(const float4*)(xst + 3072);
    stage_write((unsigned*)sx[0], r0, r1, r2, r3);
    bf16x8 aC[2][2];                                  // [sub][it]
    aC[0][0] = loadA(0, 0); aC[0][1] = loadA(0, 1);
    aC[1][0] = loadA(1, 0); aC[1][1] = loadA(1, 1);

    for (int st = 0; st < 8; ++st) {
        __syncthreads();                              // buf[st&1] ready
        float4 n0, n1, n2, n3;
        bf16x8 aN[2][2];
        if (st < 7) {
            const float* xs2 = xst + (size_t)(st + 1) * 32 * 1024;
            n0 = *(const float4*)(xs2);
            n1 = *(const float4*)(xs2 + 1024);
            n2 = *(const float4*)(xs2 + 2048);
            n3 = *(const float4*)(xs2 + 3072);
            int S0 = (st + 1) * 2;
            aN[0][0] = loadA(S0, 0);     aN[0][1] = loadA(S0, 1);
            aN[1][0] = loadA(S0 + 1, 0); aN[1][1] = loadA(S0 + 1, 1);
        }
        const unsigned* buf = sx[st & 1];
        #pragma unroll
        for (int sub = 0; sub < 2; ++sub) {
            bf16x8 b0 = loadB(buf, sub, 0);
            bf16x8 b1 = loadB(buf, sub, 1);
            acc[0][0] = __builtin_amdgcn_mfma_f32_32x32x16_bf16(aC[sub][0], b0, acc[0][0], 0, 0, 0);
            acc[0][1] = __builtin_amdgcn_mfma_f32_32x32x16_bf16(aC[sub][0], b1, acc[0][1], 0, 0, 0);
            acc[1][0] = __builtin_amdgcn_mfma_f32_32x32x16_bf16(aC[sub][1], b0, acc[1][0], 0, 0, 0);
            acc[1][1] = __builtin_amdgcn_mfma_f32_32x32x16_bf16(aC[sub][1], b1, acc[1][1], 0, 0, 0);
        }
        if (st < 7) {
            stage_write((unsigned*)sx[(st + 1) & 1], n0, n1, n2, n3);
            aC[0][0] = aN[0][0]; aC[0][1] = aN[0][1];
            aC[1][0] = aN[1][0]; aC[1][1] = aN[1][1];
        }
    }

    // epilogue: + wlast*dot, sigmoid, reduce over hw (32 cols/lane-half), atomics
    float dv0 = dptr[hw0 + wh + lw];
    float dv1 = dptr[hw0 + wh + 32 + lw];
    #pragma unroll
    for (int it = 0; it < 2; ++it) {
        int ob = by * 128 + wo + it * 32;
        #pragma unroll
        for (int r = 0; r < 16; ++r) {
            int row = (r & 3) + 8 * (r >> 2) + 4 * q;   // C/D layout (m74/m101)
            int o = ob + row;
            float wl = wlast[o];
            float z0 = acc[it][0][r] + wl * dv0;
            float z1 = acc[it][1][r] + wl * dv1;
            float a0 = __builtin_amdgcn_rcpf(1.0f + __expf(-z0));
            float a1 = __builtin_amdgcn_rcpf(1.0f + __expf(-z1));
            float xv0 = xp[(size_t)o * 1024 + hw0 + wh + lw];
            float xv1 = xp[(size_t)o * 1024 + hw0 + wh + 32 + lw];
            float sA = a0 + a1;
            float sX = a0 * xv0 + a1 * xv1;
            #pragma unroll
            for (int m = 1; m < 32; m <<= 1) {
                sA += __shfl_xor(sA, m, 64);
                sX += __shfl_xor(sX, m, 64);
            }
            if (lw == 0) {
                atomicAdd(&accA[o], sA);
                atomicAdd(&accX[o], sX);
            }
        }
    }
}

// out[b,o] = accX0/(accA0+eps) + accX1/(accA1+eps)
__global__ void k_out(const float* __restrict__ ws, float* __restrict__ out) {
    int idx = blockIdx.x * 256 + threadIdx.x;     // b*256 + o
    int b = idx >> 8, o = idx & 255;
    float a0 = ws[ACCA_OFF + b * 256 + o];
    float p0 = ws[ACCX_OFF + b * 256 + o];
    float a1 = ws[ACCA_OFF + (64 + b) * 256 + o];
    float p1 = ws[ACCX_OFF + (64 + b) * 256 + o];
    out[idx] = p0 / (a0 + 1e-8f) + p1 / (a1 + 1e-8f);
}

extern "C" void kernel_launch(void* const* d_in, const int* in_sizes, int n_in,
                              void* d_out, int out_size, void* d_ws, size_t ws_size,
                              hipStream_t stream) {
    const float* x1     = (const float*)d_in[0];
    const float* x2     = (const float*)d_in[1];
    const float* conv_w = (const float*)d_in[2];
    // d_in[3..6] (caLayer params) are dead: softmax over a size-1 axis == 1.
    float* ws  = (float*)d_ws;
    float* out = (float*)d_out;

    k_init<<<256, 256, 0, stream>>>(conv_w, ws);
    k_prep<<<512, 256, 0, stream>>>(x1, x2, ws);
    k_main<<<dim3(8, 2, 128), 256, 0, stream>>>(x1, x2, ws);
    k_out<<<64, 256, 0, stream>>>(ws, out);
}

// Round 4
// 206.425 us; speedup vs baseline: 1.8204x; 1.2077x over previous
//
#include <hip/hip_runtime.h>
#include <math.h>

// dtypes for MFMA
typedef __bf16 bf16x8 __attribute__((ext_vector_type(8)));
typedef float  f32x16 __attribute__((ext_vector_type(16)));

// ---- workspace layout (float offsets) ----
// wfrag : 65536 bf16 (fragment-ready W)          [0, 32768) floats
// wlast : 256 fp32 (column 256 of conv_w)        [32768, 33024)
// accA  : [128][256] fp32                        [164096, 196864)
// accX  : [128][256] fp32                        [196864, 229632)
#define WLAST_OFF 32768
#define ACCA_OFF  164096
#define ACCX_OFF  196864

static __device__ __forceinline__ unsigned f2bf_u(float f) {
    unsigned u = __builtin_bit_cast(unsigned, f);
    return (u + 0x7fffu + ((u >> 16) & 1u)) >> 16;                     // RNE
}
static __device__ __forceinline__ unsigned pkbf(float a, float b) {
    return (f2bf_u(b) << 16) | f2bf_u(a);                              // a in low 16
}

// DPP cross-lane add: x + move(x, CTRL) with write row-mask RM (all-VALU, no LDS pipe)
template<int CTRL, int RM>
static __device__ __forceinline__ float dpp_add(float x) {
    int yi = __builtin_amdgcn_update_dpp(0, __builtin_bit_cast(int, x), CTRL, RM, 0xF, true);
    return x + __builtin_bit_cast(float, yi);
}
// 32-lane (half-wave) sum; result valid in 16-rows 1 and 3 (lanes 16-31, 48-63)
static __device__ __forceinline__ float red32(float x) {
    x = dpp_add<0x121, 0xF>(x);   // row_ror:1
    x = dpp_add<0x122, 0xF>(x);   // row_ror:2
    x = dpp_add<0x124, 0xF>(x);   // row_ror:4
    x = dpp_add<0x128, 0xF>(x);   // row_ror:8  -> every lane has its 16-row sum
    x = dpp_add<0x142, 0xA>(x);   // row_bcast15 into rows 1,3 -> 32-lane sum there
    return x;
}

// XOR swizzle for 16-word LDS rows: breaks both mod-2 and mod-16 row aliasing;
// even shift keeps b64 pairs adjacent.
static __device__ __forceinline__ int swz(int hwr) {
    return (((hwr >> 1) ^ (hwr >> 4)) & 7) << 1;
}

// k_init: fragment-ready bf16 W + wlast + zero accumulators.
// A-frag (32x32x16): lane l holds A[o = ot*32 + (l&31)][k = S*16 + (l>>5)*8 + j], j=0..7.
// flat bf16 idx = ((S*8 + ot)*64 + l)*8 + j  -> one coalesced dwordx4/lane at use time.
__global__ void k_init(const float* __restrict__ conv_w, float* __restrict__ ws) {
    int idx = blockIdx.x * 256 + threadIdx.x;       // 0..65535
    int j  = idx & 7;
    int l  = (idx >> 3) & 63;
    int ot = (idx >> 9) & 7;
    int S  = idx >> 12;                             // 0..15
    int o  = ot * 32 + (l & 31);
    int k  = S * 16 + (l >> 5) * 8 + j;
    ((unsigned short*)ws)[idx] = (unsigned short)f2bf_u(conv_w[o * 257 + k]);
    if (idx < 256) ws[WLAST_OFF + idx] = conv_w[idx * 257 + 256];
    ws[ACCA_OFF + idx] = 0.0f;                      // zeroes accA then accX (65536 floats)
}

// k_main: per block = one image x one 64-hw tile, full 256 o, full K=256.
// Fuses: center-dot (during staging), bf16 MFMA GEMM, rank-1 dot term, sigmoid,
// row reductions (DPP) -> global atomics.
__global__ __launch_bounds__(256)
void k_main(const float* __restrict__ x1, const float* __restrict__ x2,
            float* __restrict__ ws) {
    int bx = blockIdx.x;               // hw tile: 16 x 64
    int xb = blockIdx.y;               // 0..127
    const float* xp = ((xb < 64) ? x1 : x2) + (size_t)(xb & 63) * (256 * 1024);
    const unsigned short* wfrag = (const unsigned short*)ws;
    float* accA = ws + ACCA_OFF + xb * 256;
    float* accX = ws + ACCX_OFF + xb * 256;
    int hw0 = bx * 64;

    int tid = threadIdx.x;
    int l = tid & 63, w = tid >> 6;
    int lw = l & 31, q = l >> 5;

    __shared__ unsigned sx[2][1024];   // dbuf: 64 hw-rows x 16 words (32 bf16 k)
    __shared__ float scen[256];
    __shared__ float swl[256];
    __shared__ float dotf[64];

    // cooperative loads (visible after first barrier)
    scen[tid] = xp[(size_t)tid * 1024 + 528];      // center = (16,16)
    swl[tid]  = ws[WLAST_OFF + tid];

    f32x16 acc[2][2];                  // [it: o 32-sub][jt: hw 32-sub]
    #pragma unroll
    for (int i = 0; i < 2; ++i)
        #pragma unroll
        for (int j = 0; j < 2; ++j)
            #pragma unroll
            for (int e = 0; e < 16; ++e) acc[i][j][e] = 0.0f;

    int hwi = tid & 15, kc = tid >> 4; // thread covers channels {kc*2, kc*2+1} (+32/st), hw hwi*4..+3
    const float* xst = xp + (size_t)(kc * 2) * 1024 + hw0 + hwi * 4;
    float dotp[4] = {0.f, 0.f, 0.f, 0.f};

    auto stage_write = [&](unsigned* buf, const float4& a0, const float4& a1) {
        float m0[4] = {a0.x, a0.y, a0.z, a0.w};
        float m1[4] = {a1.x, a1.y, a1.z, a1.w};
        #pragma unroll
        for (int ii = 0; ii < 4; ++ii) {
            int j = (hwi + ii) & 3;                 // rotate rows across lanes (2-way max)
            int hwr = hwi * 4 + j;
            buf[hwr * 16 + (kc ^ swz(hwr))] = pkbf(m0[j], m1[j]);
        }
    };
    auto dot_acc = [&](const float4& a0, const float4& a1, int c0) {
        float s0 = scen[c0], s1 = scen[c0 + 1];
        dotp[0] += a0.x * s0 + a1.x * s1;
        dotp[1] += a0.y * s0 + a1.y * s1;
        dotp[2] += a0.z * s0 + a1.z * s1;
        dotp[3] += a0.w * s0 + a1.w * s1;
    };
    auto loadA = [&](int S, int it) -> bf16x8 {
        return *(const bf16x8*)(wfrag + (size_t)((S * 8 + (w * 2 + it)) * 64 + l) * 8);
    };
    auto loadB = [&](const unsigned* buf, int sub, int jt) -> bf16x8 {
        int hwr = jt * 32 + lw;
        int sg = swz(hwr);
        int kb = sub * 8 + q * 4;
        uint2 p0 = *(const uint2*)&buf[hwr * 16 + (kb ^ sg)];
        uint2 p1 = *(const uint2*)&buf[hwr * 16 + ((kb + 2) ^ sg)];
        uint4 u = make_uint4(p0.x, p0.y, p1.x, p1.y);
        return __builtin_bit_cast(bf16x8, u);
    };

    // prologue: stage 0
    float4 r0 = *(const float4*)(xst);
    float4 r1 = *(const float4*)(xst + 1024);
    __syncthreads();                               // scen/swl visible
    stage_write((unsigned*)sx[0], r0, r1);
    dot_acc(r0, r1, kc * 2);
    bf16x8 aC[2][2];                               // [sub][it]
    aC[0][0] = loadA(0, 0); aC[0][1] = loadA(0, 1);
    aC[1][0] = loadA(1, 0); aC[1][1] = loadA(1, 1);

    for (int st = 0; st < 8; ++st) {
        __syncthreads();                           // sx[st&1] ready
        float4 n0, n1;
        bf16x8 aN[2][2];
        if (st < 7) {
            const float* xs2 = xst + (size_t)(st + 1) * 32 * 1024;
            n0 = *(const float4*)(xs2);
            n1 = *(const float4*)(xs2 + 1024);
            int S0 = (st + 1) * 2;
            aN[0][0] = loadA(S0, 0);     aN[0][1] = loadA(S0, 1);
            aN[1][0] = loadA(S0 + 1, 0); aN[1][1] = loadA(S0 + 1, 1);
        }
        const unsigned* buf = sx[st & 1];
        #pragma unroll
        for (int sub = 0; sub < 2; ++sub) {
            bf16x8 b0 = loadB(buf, sub, 0);
            bf16x8 b1 = loadB(buf, sub, 1);
            acc[0][0] = __builtin_amdgcn_mfma_f32_32x32x16_bf16(aC[sub][0], b0, acc[0][0], 0, 0, 0);
            acc[0][1] = __builtin_amdgcn_mfma_f32_32x32x16_bf16(aC[sub][0], b1, acc[0][1], 0, 0, 0);
            acc[1][0] = __builtin_amdgcn_mfma_f32_32x32x16_bf16(aC[sub][1], b0, acc[1][0], 0, 0, 0);
            acc[1][1] = __builtin_amdgcn_mfma_f32_32x32x16_bf16(aC[sub][1], b1, acc[1][1], 0, 0, 0);
        }
        if (st < 7) {
            stage_write((unsigned*)sx[(st + 1) & 1], n0, n1);
            dot_acc(n0, n1, (st + 1) * 32 + kc * 2);
            aC[0][0] = aN[0][0]; aC[0][1] = aN[0][1];
            aC[1][0] = aN[1][0]; aC[1][1] = aN[1][1];
        }
    }

    // dot reduction: sx[0] free (last read at st=6, barrier at st=7 passed); sx[1] untouched.
    float* sd = (float*)sx[0];                     // [64 hw][16 kc]
    #pragma unroll
    for (int j = 0; j < 4; ++j)
        sd[(hwi * 4 + j) * 16 + kc] = dotp[j];
    __syncthreads();
    if (tid < 64) {
        float s = 0.f;
        #pragma unroll
        for (int k = 0; k < 16; ++k) s += sd[tid * 16 + k];
        dotf[tid] = s * (1.0f / 256.0f);
    }
    __syncthreads();

    // epilogue: z += wlast*dot; attn = sigmoid(z); DPP-reduce over 32 hw lanes; atomics
    float dv0 = dotf[lw];
    float dv1 = dotf[32 + lw];
    #pragma unroll
    for (int it = 0; it < 2; ++it) {
        int ob = w * 64 + it * 32;
        #pragma unroll
        for (int r = 0; r < 16; ++r) {
            int row = (r & 3) + 8 * (r >> 2) + 4 * q;   // C/D layout (m74/m101)
            int o = ob + row;
            float wl = swl[o];
            float z0 = acc[it][0][r] + wl * dv0;
            float z1 = acc[it][1][r] + wl * dv1;
            float a0 = 1.0f / (1.0f + __expf(-z0));
            float a1 = 1.0f / (1.0f + __expf(-z1));
            float xv0 = xp[(size_t)o * 1024 + hw0 + lw];        // L2-hot (just staged)
            float xv1 = xp[(size_t)o * 1024 + hw0 + 32 + lw];
            float sA = red32(a0 + a1);
            float sX = red32(a0 * xv0 + a1 * xv1);
            if (lw == 31) {                                     // lanes 31,63 hold 32-sums
                atomicAdd(&accA[o], sA);
                atomicAdd(&accX[o], sX);
            }
        }
    }
}

// out[b,o] = accX0/(accA0+eps) + accX1/(accA1+eps)
__global__ void k_out(const float* __restrict__ ws, float* __restrict__ out) {
    int idx = blockIdx.x * 256 + threadIdx.x;     // b*256 + o
    int b = idx >> 8, o = idx & 255;
    float a0 = ws[ACCA_OFF + b * 256 + o];
    float p0 = ws[ACCX_OFF + b * 256 + o];
    float a1 = ws[ACCA_OFF + (64 + b) * 256 + o];
    float p1 = ws[ACCX_OFF + (64 + b) * 256 + o];
    out[idx] = p0 / (a0 + 1e-8f) + p1 / (a1 + 1e-8f);
}

extern "C" void kernel_launch(void* const* d_in, const int* in_sizes, int n_in,
                              void* d_out, int out_size, void* d_ws, size_t ws_size,
                              hipStream_t stream) {
    const float* x1     = (const float*)d_in[0];
    const float* x2     = (const float*)d_in[1];
    const float* conv_w = (const float*)d_in[2];
    // d_in[3..6] (caLayer params) are dead: softmax over a size-1 axis == 1.
    float* ws  = (float*)d_ws;
    float* out = (float*)d_out;

    k_init<<<256, 256, 0, stream>>>(conv_w, ws);
    k_main<<<dim3(16, 128), 256, 0, stream>>>(x1, x2, ws);
    k_out<<<64, 256, 0, stream>>>(ws, out);
}